// Round 14
// baseline (533.347 us; speedup 1.0000x reference)
//
#include <hip/hip_runtime.h>

// GNN: N=50000 nodes, E=800000 edges, H=64, L=2.
// R20 = R19 (best, 531.6us) + bijective XCD-chunked block swizzle on the two
// edge kernels (guide T1, m204 bijective variant; nwg=12500 not %8==0).
// Rationale: 8 XCDs x 4MB private L2; default round-robin spreads consecutive
// dst-sorted blocks across XCDs so every XCD sees the full 25.6MB Ps/Pd
// footprint. Chunked swizzle gives each XCD a contiguous dst range -> Pd
// (~1.6MB/XCD) fits L2; agg atomics localize too. Pure index remap, bijective,
// correctness independent of HW mapping. Everything else identical to R19.
// Pipeline: conv_w(+fuse,+deg0) | deg | scan | fill+encode(+agg0) |
//           edge_l0(+agg) | node_l0(+agg0) | edge_l1(+agg) | node_l1+dec.

#define NN 50000
#define EE 800000
#define HH 64
#define LDK 72   // bf16 plane leading dim (144 B row)
#define EPB 64   // rows per block
#define NXCD 8

typedef short short8 __attribute__((ext_vector_type(8)));
typedef short short4v __attribute__((ext_vector_type(4)));
typedef float f32x4 __attribute__((ext_vector_type(4)));
typedef unsigned uint4v __attribute__((ext_vector_type(4)));

#define MFMA __builtin_amdgcn_mfma_f32_16x16x32_bf16

// wt slots (each 8192 ushorts: 4096 hi + 4096 lo, layout [f][k])
#define S_WE2   0
#define S_W1E0  1
#define S_W2E0  2
#define S_W1E1  3
#define S_W2E1  4
#define S_WN2   5
#define S_W1S0  6
#define S_W1D0  7
#define S_W1S1  8
#define S_W1D1  9
#define S_W1NX0 10
#define S_W1NA0 11
#define S_W2N0  12
#define S_W1NX1 13
#define S_W1NA1 14
#define S_W2N1  15
#define S_DW1   16
#define S_WE21  17  // We2(l0e) @ W1e(l0)
#define S_WNS0  18  // wn2 @ W1s(l0)
#define S_WND0  19  // wn2 @ W1d(l0)
#define OFF_WE1 (20*8192)          // [f][32], K=4 padded (legacy, unused by edge_l0 now)
#define OFF_WN1 (20*8192+4096)     // [f][32], K=8 padded
#define FB_OFF  (20*8192+8192)     // ushort offset of float fused biases
// fb floats: [0..63]=be2@W1e, [64..127]=bn2@W1s0, [128..191]=bn2@W1d0
#define WT_USHORTS (20*8192+8192+384)

// bijective XCD-chunked swizzle (m204 variant): each XCD gets a contiguous
// chunk of work ids, assuming blockIdx round-robins XCDs; bijective always.
__device__ __forceinline__ int xcd_swizzle(int bid, int nwg) {
    const int xcd = bid & (NXCD - 1);
    const int idx = bid >> 3;
    const int q = nwg >> 3, r = nwg & (NXCD - 1);
    return (xcd < r ? xcd * (q + 1) : r * (q + 1) + (xcd - r) * q) + idx;
}

// ---------------- bf16 helpers ----------------

__device__ __forceinline__ void split2(float x, unsigned short& h, unsigned short& l) {
    union { float f; unsigned u; } a, hf, b;
    a.f = x;
    const unsigned hb = (a.u + 0x7FFFu + ((a.u >> 16) & 1u)) >> 16;  // RNE hi
    hf.u = hb << 16;
    b.f = x - hf.f;                  // exact
    h = (unsigned short)hb;
    l = (unsigned short)(b.u >> 16); // truncated lo: err <= 2^-16 |x|
}

__device__ __forceinline__ float bf2f(unsigned short s) {
    union { unsigned u; float f; } a; a.u = ((unsigned)s) << 16; return a.f;
}

// packed split (numerics == split2, verified R11-R19 absmax-identical)
__device__ __forceinline__ unsigned cvtpk_bf16(float a, float b) {
    unsigned r;
    asm("v_cvt_pk_bf16_f32 %0, %1, %2" : "=v"(r) : "v"(a), "v"(b));
    return r;
}
__device__ __forceinline__ void split_pair(float x0, float x1, unsigned& hw, unsigned& lw) {
    hw = cvtpk_bf16(x0, x1);
    union { unsigned u; float f; } h0, h1, r0, r1;
    h0.u = hw << 16;
    h1.u = hw & 0xFFFF0000u;
    r0.f = x0 - h0.f;
    r1.f = x1 - h1.f;
    lw = (r0.u >> 16) | (r1.u & 0xFFFF0000u);
}

// non-temporal 16B helpers (bypass L2 allocation for streamed epk)
__device__ __forceinline__ void nt_store16(void* p, const void* v) {
    __builtin_nontemporal_store(*(const uint4v*)v, (uint4v*)p);
}
__device__ __forceinline__ void nt_load16(void* dst, const void* p) {
    *(uint4v*)dst = __builtin_nontemporal_load((const uint4v*)p);
}

// A-frags for one 16-feature slice of a 64x64 weight: [chunk][plane]
__device__ __forceinline__ void load_wf(const unsigned short* __restrict__ wm,
                                        int ft, int l15, int quad, short8 (&w)[2][2]) {
#pragma unroll
    for (int c = 0; c < 2; ++c) {
        const int el = (ft * 16 + l15) * 64 + c * 32 + quad * 8;
        w[c][0] = *(const short8*)(wm + el);
        w[c][1] = *(const short8*)(wm + 4096 + el);
    }
}

// D += Ah*Bh + Al*Bh + Ah*Bl over K=64 (2 chunks)
__device__ __forceinline__ f32x4 chain6(const short8 (&w)[2][2],
                                        short8 bh0, short8 bh1,
                                        short8 bl0, short8 bl1, f32x4 a) {
    a = MFMA(w[0][0], bh0, a, 0, 0, 0);
    a = MFMA(w[1][0], bh1, a, 0, 0, 0);
    a = MFMA(w[0][1], bh0, a, 0, 0, 0);
    a = MFMA(w[1][1], bh1, a, 0, 0, 0);
    a = MFMA(w[0][0], bl0, a, 0, 0, 0);
    a = MFMA(w[1][0], bl1, a, 0, 0, 0);
    return a;
}

// one row-tile GEMM step: acc += W @ B(row e)
__device__ __forceinline__ void gemm_tile(const unsigned short* pHi, const unsigned short* pLo,
                                          const short8 (&w)[2][2], int e, int quad, f32x4& a) {
    const short8 bh0 = *(const short8*)(pHi + e * LDK + quad * 8);
    const short8 bh1 = *(const short8*)(pHi + e * LDK + 32 + quad * 8);
    const short8 bl0 = *(const short8*)(pLo + e * LDK + quad * 8);
    const short8 bl1 = *(const short8*)(pLo + e * LDK + 32 + quad * 8);
    a = chain6(w, bh0, bh1, bl0, bl1, a);
}

// store 4 feats of row e via packed cvt split
__device__ __forceinline__ void store_row4(unsigned short* pHi, unsigned short* pLo,
                                           const f32x4& a, int e, int f0) {
    unsigned hw0, lw0, hw1, lw1;
    split_pair(a[0], a[1], hw0, lw0);
    split_pair(a[2], a[3], hw1, lw1);
    uint2 hv; hv.x = hw0; hv.y = hw1;
    uint2 lv; lv.x = lw0; lv.y = lw1;
    *(uint2*)(pHi + e * LDK + f0) = hv;
    *(uint2*)(pLo + e * LDK + f0) = lv;
}

// ======== 4-tile helpers (256 thr) ========

__device__ __forceinline__ void gemm_planes(const unsigned short* pHi, const unsigned short* pLo,
                                            const short8 (&w)[2][2], int l15, int quad,
                                            f32x4 (&acc)[4]) {
#pragma unroll
    for (int et = 0; et < 4; ++et) {
        const int e = et * 16 + l15;
        gemm_tile(pHi, pLo, w, e, quad, acc[et]);
    }
}

__device__ __forceinline__ void set_bias(f32x4 (&acc)[4], const float* __restrict__ b, int f0) {
    const float4 b4 = *(const float4*)(b + f0);
#pragma unroll
    for (int et = 0; et < 4; ++et) {
        acc[et][0] = b4.x; acc[et][1] = b4.y; acc[et][2] = b4.z; acc[et][3] = b4.w;
    }
}

__device__ __forceinline__ void set_zero(f32x4 (&acc)[4]) {
#pragma unroll
    for (int et = 0; et < 4; ++et)
#pragma unroll
        for (int r = 0; r < 4; ++r) acc[et][r] = 0.f;
}

__device__ __forceinline__ void relu4(f32x4 (&acc)[4]) {
#pragma unroll
    for (int et = 0; et < 4; ++et)
#pragma unroll
        for (int r = 0; r < 4; ++r) acc[et][r] = fmaxf(acc[et][r], 0.f);
}

__device__ __forceinline__ void store_split_planes(unsigned short* pHi, unsigned short* pLo,
                                                   const f32x4 (&acc)[4], int l15, int f0) {
#pragma unroll
    for (int et = 0; et < 4; ++et) store_row4(pHi, pLo, acc[et], et * 16 + l15, f0);
}

// stage fp32 [64][64] tile -> split hi/lo planes; invalid rows zero
__device__ __forceinline__ void stage_split64(unsigned short* pHi, unsigned short* pLo,
                                              const float* g, long rowBase, int t, int nValid) {
    const int row = t >> 2, q = t & 3;
    const bool valid = row < nValid;
#pragma unroll
    for (int i = 0; i < 4; ++i) {
        const int col = q * 16 + i * 4;
        float4 v = make_float4(0.f, 0.f, 0.f, 0.f);
        if (valid) v = *(const float4*)(g + (size_t)(rowBase + row) * HH + col);
        unsigned hw0, lw0, hw1, lw1;
        split_pair(v.x, v.y, hw0, lw0);
        split_pair(v.z, v.w, hw1, lw1);
        uint2 hv; hv.x = hw0; hv.y = hw1;
        uint2 lv; lv.x = lw0; lv.y = lw1;
        *(uint2*)(pHi + row * LDK + col) = hv;
        *(uint2*)(pLo + row * LDK + col) = lv;
    }
}

// in-LDS segment sum over dst-sorted rows + atomic scatter (64 rows, 4 waves)
__device__ __forceinline__ void segsum_atomic(const unsigned short* pHi, const unsigned short* pLo,
                                              const int* sDst, int t,
                                              float* __restrict__ agg) {
    const int f = t & 63, c0 = (t >> 6) * 16;
    float s = 0.f;
    int d = sDst[c0];
#pragma unroll
    for (int i = 0; i < 16; ++i) {
        const int r = c0 + i;
        s += bf2f(pHi[r * LDK + f]) + bf2f(pLo[r * LDK + f]);
        const int dn = (i == 15) ? -1 : sDst[r + 1];
        if (dn != d) {
            atomicAdd(&agg[(size_t)d * HH + f], s);
            s = 0.f; d = dn;
        }
    }
}

// ---------------- setup: weights + fused products + deg zero (one kernel) -------

__global__ void k_conv_w(const float* __restrict__ enc_n_w1, const float* __restrict__ enc_n_w2,
                         const float* __restrict__ enc_e_w1, const float* __restrict__ enc_e_w2,
                         const float* __restrict__ pe_w1, const float* __restrict__ pe_w2,
                         const float* __restrict__ pn_w1, const float* __restrict__ pn_w2,
                         const float* __restrict__ dw1,
                         const float* __restrict__ enc_n_b2, const float* __restrict__ enc_e_b2,
                         unsigned short* __restrict__ wt, unsigned* __restrict__ deg)
{
    const int i = blockIdx.x * 256 + threadIdx.x;
    if (i < 17 * 4096) {
        const int m = i >> 12, r = i & 4095;
        const int f = r & 63, k = r >> 6;
        const float* W;
        switch (m) {
            case S_WE2:   W = enc_e_w2; break;
            case S_W1E0:  W = pe_w1; break;
            case S_W2E0:  W = pe_w2; break;
            case S_W1E1:  W = pe_w1 + 192 * 64; break;
            case S_W2E1:  W = pe_w2 + 64 * 64; break;
            case S_WN2:   W = enc_n_w2; break;
            case S_W1S0:  W = pe_w1 + 64 * 64; break;
            case S_W1D0:  W = pe_w1 + 128 * 64; break;
            case S_W1S1:  W = pe_w1 + 192 * 64 + 64 * 64; break;
            case S_W1D1:  W = pe_w1 + 192 * 64 + 128 * 64; break;
            case S_W1NX0: W = pn_w1; break;
            case S_W1NA0: W = pn_w1 + 64 * 64; break;
            case S_W2N0:  W = pn_w2; break;
            case S_W1NX1: W = pn_w1 + 128 * 64; break;
            case S_W1NA1: W = pn_w1 + 128 * 64 + 64 * 64; break;
            case S_W2N1:  W = pn_w2 + 64 * 64; break;
            default:      W = dw1; break;
        }
        unsigned short h, l; split2(W[r], h, l);    // W[k*64+f]
        wt[m * 8192 + f * 64 + k] = h;
        wt[m * 8192 + 4096 + f * 64 + k] = l;
    } else if (i < 17 * 4096 + 2048) {
        const int r = i - 17 * 4096, f = r >> 5, k = r & 31;
        const float v = (k < 4) ? enc_e_w1[k * 64 + f] : 0.f;
        unsigned short h, l; split2(v, h, l);
        wt[OFF_WE1 + f * 32 + k] = h;
        wt[OFF_WE1 + 2048 + f * 32 + k] = l;
    } else if (i < 17 * 4096 + 4096) {
        const int r = i - 17 * 4096 - 2048, f = r >> 5, k = r & 31;
        const float v = (k < 8) ? enc_n_w1[k * 64 + f] : 0.f;
        unsigned short h, l; split2(v, h, l);
        wt[OFF_WN1 + f * 32 + k] = h;
        wt[OFF_WN1 + 2048 + f * 32 + k] = l;
    } else if (i < 73728 + 3 * 4096) {
        // fused weight products (fp32)
        const int r = i - 73728;
        const int m = r >> 12, rr = r & 4095;
        const int g = rr & 63, j = rr >> 6;
        const float* A = (m == 0) ? enc_e_w2 : enc_n_w2;
        const float* B = pe_w1 + m * 64 * 64;   // m0: e-slice, m1: src, m2: dst
        float s = 0.f;
#pragma unroll 8
        for (int f = 0; f < 64; ++f) s += A[j * 64 + f] * B[f * 64 + g];
        unsigned short h, l; split2(s, h, l);
        wt[(S_WE21 + m) * 8192 + g * 64 + j] = h;
        wt[(S_WE21 + m) * 8192 + 4096 + g * 64 + j] = l;
    } else if (i < 73728 + 3 * 4096 + 192) {
        const int r = i - 73728 - 3 * 4096;
        const int m = r >> 6, g = r & 63;
        const float* bb = (m == 0) ? enc_e_b2 : enc_n_b2;
        const float* B = pe_w1 + m * 64 * 64;
        float s = 0.f;
#pragma unroll 8
        for (int f = 0; f < 64; ++f) s += bb[f] * B[f * 64 + g];
        float* fbp = (float*)(wt + FB_OFF);
        fbp[m * 64 + g] = s;
    } else if (i < 73728 + 3 * 4096 + 192 + NN) {
        deg[i - (73728 + 3 * 4096 + 192)] = 0u;   // replaces memset(deg)
    }
}

// ---------------- CSR build ----------------

__global__ void k_deg(const int* __restrict__ eidx, unsigned* __restrict__ deg) {
    const int e = blockIdx.x * 256 + threadIdx.x;
    if (e < EE) atomicAdd(&deg[eidx[EE + e]], 1u);
}

__global__ __launch_bounds__(1024) void k_scan(unsigned* deg, unsigned* __restrict__ off) {
    __shared__ unsigned part[1024];
    const int t = threadIdx.x;
    const int CH = 52;                    // 1024*52 = 53248 >= NN; 52*4B 16B-aligned
    const int s = t * CH;
    unsigned v[52];
    unsigned sum = 0;
#pragma unroll
    for (int j = 0; j < 13; ++j) {
        const int i = s + j * 4;
        uint4 u = {0u, 0u, 0u, 0u};
        if (i + 3 < NN) {
            u = *(const uint4*)(deg + i);
        } else {
            if (i < NN)     u.x = deg[i];
            if (i + 1 < NN) u.y = deg[i + 1];
            if (i + 2 < NN) u.z = deg[i + 2];
            if (i + 3 < NN) u.w = deg[i + 3];
        }
        v[j * 4] = u.x; v[j * 4 + 1] = u.y; v[j * 4 + 2] = u.z; v[j * 4 + 3] = u.w;
        sum += u.x + u.y + u.z + u.w;
    }
    part[t] = sum;
    __syncthreads();
    for (int d = 1; d < 1024; d <<= 1) {
        unsigned p = (t >= d) ? part[t - d] : 0u;
        __syncthreads();
        if (t >= d) part[t] += p;
        __syncthreads();
    }
    unsigned base = (t > 0) ? part[t - 1] : 0u;
#pragma unroll
    for (int j = 0; j < 13; ++j) {
        const int i = s + j * 4;
        uint4 o;
        o.x = base; base += v[j * 4];
        o.y = base; base += v[j * 4 + 1];
        o.z = base; base += v[j * 4 + 2];
        o.w = base; base += v[j * 4 + 3];
        if (i + 3 < NN) {
            *(uint4*)(off + i) = o;
            *(uint4*)(deg + i) = o;       // reuse as fill cursor
        } else {
            if (i < NN)     { off[i] = o.x;     deg[i] = o.x; }
            if (i + 1 < NN) { off[i + 1] = o.y; deg[i + 1] = o.y; }
            if (i + 2 < NN) { off[i + 2] = o.z; deg[i + 2] = o.z; }
            if (i + 3 < NN) { off[i + 3] = o.w; deg[i + 3] = o.w; }
        }
    }
    if (t == 1023) off[NN] = part[1023];
}

// ---------------- K1': CSR fill + node encoder (combined grid) ----------------
// blocks [0, 3125): fill; blocks [3125, 3125+782): encode (+ zero agg slice).

#define FILL_BLOCKS 3125

__global__ __launch_bounds__(256, 4) void k_fill_encode(
    const int* __restrict__ eidx, unsigned* __restrict__ cur,
    int* __restrict__ csr, int2* __restrict__ sd,
    const float* __restrict__ x, const unsigned short* __restrict__ wt,
    const float* __restrict__ fb,
    const float* __restrict__ bn1, const float* __restrict__ bn2,
    float* __restrict__ x_h, float* __restrict__ Ps, float* __restrict__ Pd,
    float* __restrict__ agg)
{
    __shared__ unsigned short pXhi[EPB * LDK], pXlo[EPB * LDK];
    __shared__ unsigned short pHhi[EPB * LDK], pHlo[EPB * LDK];

    if (blockIdx.x < FILL_BLOCKS) {
        const int e = blockIdx.x * 256 + threadIdx.x;
        if (e < EE) {
            const int s = eidx[e];
            const int d = eidx[EE + e];
            const unsigned p = atomicAdd(&cur[d], 1u);
            csr[p] = e;
            sd[p] = make_int2(s, d);
        }
        return;
    }

    const int t = threadIdx.x;
    const int lane = t & 63, ft = t >> 6;
    const int quad = lane >> 4, l15 = lane & 15;
    const int f0 = ft * 16 + quad * 4;
    const int nodeBase = (blockIdx.x - FILL_BLOCKS) * 64;
    const int nValid = min(64, NN - nodeBase);

    // zero agg slice (replaces memset#1; consumed by edge_l0 later)
    {
        const uint4 z4 = {0u, 0u, 0u, 0u};
        uint4* ag = (uint4*)(agg + (size_t)nodeBase * HH);
#pragma unroll
        for (int j = 0; j < 4; ++j) {
            const int di = t + j * 256;             // uint4 idx 0..1023
            if (nodeBase + (di >> 4) < NN) ag[di] = z4;
        }
    }

    // hoist phase1 weight frags (overlap with x staging)
    short8 wN1a, wN1b;
    {
        const int el = (ft * 16 + l15) * 32 + quad * 8;
        wN1a = *(const short8*)(wt + OFF_WN1 + el);
        wN1b = *(const short8*)(wt + OFF_WN1 + 2048 + el);
    }

    // stage x (8 cols) padded to 32
    {
        const int row = t >> 2, q = t & 3;
        if (q == 0) {
            float4 a0 = make_float4(0.f, 0.f, 0.f, 0.f), a1 = a0;
            if (row < nValid) {
                a0 = *(const float4*)(x + (size_t)(nodeBase + row) * 8);
                a1 = *(const float4*)(x + (size_t)(nodeBase + row) * 8 + 4);
            }
            unsigned hw0, lw0, hw1, lw1, hw2, lw2, hw3, lw3;
            split_pair(a0.x, a0.y, hw0, lw0);
            split_pair(a0.z, a0.w, hw1, lw1);
            split_pair(a1.x, a1.y, hw2, lw2);
            split_pair(a1.z, a1.w, hw3, lw3);
            uint4 H; H.x = hw0; H.y = hw1; H.z = hw2; H.w = hw3;
            uint4 L; L.x = lw0; L.y = lw1; L.z = lw2; L.w = lw3;
            *(uint4*)(pXhi + row * LDK) = H;
            *(uint4*)(pXlo + row * LDK) = L;
        } else {
            const uint4 z = {0u, 0u, 0u, 0u};
            *(uint4*)(pXhi + row * LDK + q * 8) = z;
            *(uint4*)(pXlo + row * LDK + q * 8) = z;
        }
    }
    __syncthreads();

    f32x4 acc[4];

    // phase1: h1 = relu(x @ wn1 + bn1) -> pH
    {
        set_bias(acc, bn1, f0);
#pragma unroll
        for (int et = 0; et < 4; ++et) {
            const int e = et * 16 + l15;
            const short8 bh0 = *(const short8*)(pXhi + e * LDK + quad * 8);
            const short8 bl0 = *(const short8*)(pXlo + e * LDK + quad * 8);
            f32x4 a = acc[et];
            a = MFMA(wN1a, bh0, a, 0, 0, 0);
            a = MFMA(wN1b, bh0, a, 0, 0, 0);
            a = MFMA(wN1a, bl0, a, 0, 0, 0);
            acc[et] = a;
        }
        relu4(acc);
        store_split_planes(pHhi, pHlo, acc, l15, f0);
    }
    __syncthreads();

    // phase2' (fused, read-only on pH):
    // x_h = h1 @ wn2 + bn2
    {
        short8 w[2][2];
        load_wf(wt + S_WN2 * 8192, ft, l15, quad, w);
        set_bias(acc, bn2, f0);
        gemm_planes(pHhi, pHlo, w, l15, quad, acc);
#pragma unroll
        for (int et = 0; et < 4; ++et) {
            const int r = et * 16 + l15;
            if (r < nValid) {
                float4 v = make_float4(acc[et][0], acc[et][1], acc[et][2], acc[et][3]);
                *(float4*)(x_h + (size_t)(nodeBase + r) * HH + f0) = v;
            }
        }
    }
    // Ps = h1 @ (wn2*W1s0) + bn2@W1s0
    {
        short8 w[2][2];
        load_wf(wt + S_WNS0 * 8192, ft, l15, quad, w);
        set_bias(acc, fb + 64, f0);
        gemm_planes(pHhi, pHlo, w, l15, quad, acc);
#pragma unroll
        for (int et = 0; et < 4; ++et) {
            const int r = et * 16 + l15;
            if (r < nValid) {
                float4 v = make_float4(acc[et][0], acc[et][1], acc[et][2], acc[et][3]);
                *(float4*)(Ps + (size_t)(nodeBase + r) * HH + f0) = v;
            }
        }
    }
    // Pd = h1 @ (wn2*W1d0) + bn2@W1d0
    {
        short8 w[2][2];
        load_wf(wt + S_WND0 * 8192, ft, l15, quad, w);
        set_bias(acc, fb + 128, f0);
        gemm_planes(pHhi, pHlo, w, l15, quad, acc);
#pragma unroll
        for (int et = 0; et < 4; ++et) {
            const int r = et * 16 + l15;
            if (r < nValid) {
                float4 v = make_float4(acc[et][0], acc[et][1], acc[et][2], acc[et][3]);
                *(float4*)(Pd + (size_t)(nodeBase + r) * HH + f0) = v;
            }
        }
    }
}

// ---------------- K2: edge encoder + layer-0 edge MLP + fused agg ----------------
// phase1 fp32 VALU (K=4); weight frags hoisted; epk non-temporal; XCD swizzle.

__global__ __launch_bounds__(256, 4) void k_edge_l0(
    const float* __restrict__ eattr, const int* __restrict__ csr,
    const int2* __restrict__ sd,
    const float* __restrict__ Ps, const float* __restrict__ Pd,
    const float* __restrict__ we1, const float* __restrict__ be1,
    const float* __restrict__ be2,
    const unsigned short* __restrict__ wt, const float* __restrict__ fb,
    const float* __restrict__ pb1, const float* __restrict__ pb2,
    unsigned short* __restrict__ epkHi, unsigned short* __restrict__ epkLo,
    float* __restrict__ agg)
{
    __shared__ unsigned short pHhi[EPB * LDK], pHlo[EPB * LDK];
    __shared__ unsigned short pEhi[EPB * LDK], pElo[EPB * LDK];
    __shared__ int sDst[EPB];

    const int t = threadIdx.x;
    const int lane = t & 63, ft = t >> 6;
    const int quad = lane >> 4, l15 = lane & 15;
    const int f0 = ft * 16 + quad * 4;
    const int wg = xcd_swizzle(blockIdx.x, gridDim.x);
    const long eBase = (long)wg * EPB;

    int srcs[4], dsts[4];
    float4 ea[4];
#pragma unroll
    for (int et = 0; et < 4; ++et) {
        const long p = eBase + et * 16 + l15;
        const int2 v = sd[p];
        srcs[et] = v.x;
        dsts[et] = v.y;
        const int eid = csr[p];
        ea[et] = *(const float4*)(eattr + (size_t)eid * 4);
    }
    if (t < EPB) sDst[t] = sd[eBase + t].y;

    // prefetch Ps/Pd gathers (consumed in fused phase2')
    float4 ps[4], pd[4];
#pragma unroll
    for (int et = 0; et < 4; ++et) {
        ps[et] = *(const float4*)(Ps + (size_t)srcs[et] * HH + f0);
        pd[et] = *(const float4*)(Pd + (size_t)dsts[et] * HH + f0);
    }
    // hoist ALL weight frags (3 sets, overlap with the gathers above)
    short8 wE2[2][2], wE21[2][2], wW2[2][2];
    load_wf(wt + S_WE2 * 8192, ft, l15, quad, wE2);
    load_wf(wt + S_WE21 * 8192, ft, l15, quad, wE21);
    load_wf(wt + S_W2E0 * 8192, ft, l15, quad, wW2);

    f32x4 acc[4];

    // phase1 (fp32 VALU, K=4): h0 = relu(eattr @ We1 + be1) -> pE
    {
        const float4 w0 = *(const float4*)(we1 + 0 * HH + f0);
        const float4 w1 = *(const float4*)(we1 + 1 * HH + f0);
        const float4 w2 = *(const float4*)(we1 + 2 * HH + f0);
        const float4 w3 = *(const float4*)(we1 + 3 * HH + f0);
        const float4 b1 = *(const float4*)(be1 + f0);
#pragma unroll
        for (int et = 0; et < 4; ++et) {
            const int e = et * 16 + l15;
            f32x4 a;
            a[0] = fmaf(ea[et].x, w0.x, fmaf(ea[et].y, w1.x,
                   fmaf(ea[et].z, w2.x, fmaf(ea[et].w, w3.x, b1.x))));
            a[1] = fmaf(ea[et].x, w0.y, fmaf(ea[et].y, w1.y,
                   fmaf(ea[et].z, w2.y, fmaf(ea[et].w, w3.y, b1.y))));
            a[2] = fmaf(ea[et].x, w0.z, fmaf(ea[et].y, w1.z,
                   fmaf(ea[et].z, w2.z, fmaf(ea[et].w, w3.z, b1.z))));
            a[3] = fmaf(ea[et].x, w0.w, fmaf(ea[et].y, w1.w,
                   fmaf(ea[et].z, w2.w, fmaf(ea[et].w, w3.w, b1.w))));
#pragma unroll
            for (int r = 0; r < 4; ++r) a[r] = fmaxf(a[r], 0.f);
            store_row4(pEhi, pElo, a, e, f0);
        }
    }
    __syncthreads();

    // phase2' (fused, SINGLE LDS read of h0 per tile feeds BOTH chains):
    // e0 = h0 @ We2 + be2 (regs residual); t1 = relu(h0 @ WE21 + fb + pb1 + Ps + Pd) -> pH
    f32x4 e0s[4];
    {
        const float4 b2 = *(const float4*)(be2 + f0);
        const float4 fa = *(const float4*)(fb + f0);       // be2@W1e
        const float4 p1 = *(const float4*)(pb1 + f0);
        const float4 tb = make_float4(fa.x + p1.x, fa.y + p1.y,
                                      fa.z + p1.z, fa.w + p1.w);
#pragma unroll
        for (int et = 0; et < 4; ++et) {
            const int e = et * 16 + l15;
            const short8 bh0 = *(const short8*)(pEhi + e * LDK + quad * 8);
            const short8 bh1 = *(const short8*)(pEhi + e * LDK + 32 + quad * 8);
            const short8 bl0 = *(const short8*)(pElo + e * LDK + quad * 8);
            const short8 bl1 = *(const short8*)(pElo + e * LDK + 32 + quad * 8);
            f32x4 a; a[0] = b2.x; a[1] = b2.y; a[2] = b2.z; a[3] = b2.w;
            a = chain6(wE2, bh0, bh1, bl0, bl1, a);
            e0s[et] = a;
            f32x4 b = {0.f, 0.f, 0.f, 0.f};
            b = chain6(wE21, bh0, bh1, bl0, bl1, b);
            b[0] = fmaxf(b[0] + ps[et].x + pd[et].x + tb.x, 0.f);
            b[1] = fmaxf(b[1] + ps[et].y + pd[et].y + tb.y, 0.f);
            b[2] = fmaxf(b[2] + ps[et].z + pd[et].z + tb.z, 0.f);
            b[3] = fmaxf(b[3] + ps[et].w + pd[et].w + tb.w, 0.f);
            store_row4(pHhi, pHlo, b, e, f0);
        }
    }
    __syncthreads();

    // phase3': e1 = e0(regs) + t1 @ W2e + pb2 -> pE
    {
        set_zero(acc);
        gemm_planes(pHhi, pHlo, wW2, l15, quad, acc);
        const float4 b4 = *(const float4*)(pb2 + f0);
#pragma unroll
        for (int et = 0; et < 4; ++et) {
            acc[et][0] += e0s[et][0] + b4.x;
            acc[et][1] += e0s[et][1] + b4.y;
            acc[et][2] += e0s[et][2] + b4.z;
            acc[et][3] += e0s[et][3] + b4.w;
        }
        store_split_planes(pEhi, pElo, acc, l15, f0);
    }
    __syncthreads();

    // pack pE -> epk planes (pure uint4 copies, NON-TEMPORAL stores)
    {
        const int row = t >> 2, q = t & 3;
#pragma unroll
        for (int half = 0; half < 2; ++half) {
            const int lo = row * LDK + q * 8 + half * 32;
            const long go = (eBase + row) * HH + q * 8 + half * 32;
            uint4 hv = *(const uint4*)(pEhi + lo);
            uint4 lv = *(const uint4*)(pElo + lo);
            nt_store16(epkHi + go, &hv);
            nt_store16(epkLo + go, &lv);
        }
    }
    // fused aggregation: agg[dst] += e1
    segsum_atomic(pEhi, pElo, sDst, t, agg);
}

// ---------------- K4: layer-1 edge MLP + fused agg ----------------

__global__ __launch_bounds__(256, 4) void k_edge_l1(
    const int2* __restrict__ sd,
    const float* __restrict__ Ps, const float* __restrict__ Pd,
    const unsigned short* __restrict__ wt,
    const float* __restrict__ pb1, const float* __restrict__ pb2,
    const unsigned short* __restrict__ epkHi, const unsigned short* __restrict__ epkLo,
    float* __restrict__ agg)
{
    __shared__ unsigned short pEhi[EPB * LDK], pElo[EPB * LDK];
    __shared__ unsigned short pHhi[EPB * LDK], pHlo[EPB * LDK];
    __shared__ int sDst[EPB];

    const int t = threadIdx.x;
    const int lane = t & 63, ft = t >> 6;
    const int quad = lane >> 4, l15 = lane & 15;
    const int f0 = ft * 16 + quad * 4;
    const int wg = xcd_swizzle(blockIdx.x, gridDim.x);
    const long eBase = (long)wg * EPB;

    // load epk planes -> pE (pure uint4 copies, NON-TEMPORAL loads)
    {
        const int row = t >> 2, q = t & 3;
#pragma unroll
        for (int half = 0; half < 2; ++half) {
            const int lo = row * LDK + q * 8 + half * 32;
            const long go = (eBase + row) * HH + q * 8 + half * 32;
            uint4 hv, lv;
            nt_load16(&hv, epkHi + go);
            nt_load16(&lv, epkLo + go);
            *(uint4*)(pEhi + lo) = hv;
            *(uint4*)(pElo + lo) = lv;
        }
    }
    if (t < EPB) sDst[t] = sd[eBase + t].y;

    int srcs[4], dsts[4];
#pragma unroll
    for (int et = 0; et < 4; ++et) {
        const long p = eBase + et * 16 + l15;
        const int2 v = sd[p];
        srcs[et] = v.x;
        dsts[et] = v.y;
    }
    // prefetch Ps/Pd gathers (consumed in t1 phase)
    float4 ps[4], pd[4];
#pragma unroll
    for (int et = 0; et < 4; ++et) {
        ps[et] = *(const float4*)(Ps + (size_t)srcs[et] * HH + f0);
        pd[et] = *(const float4*)(Pd + (size_t)dsts[et] * HH + f0);
    }
    // hoist both weight sets (overlap with staging/gathers)
    short8 wT1[2][2], wE2[2][2];
    load_wf(wt + S_W1E1 * 8192, ft, l15, quad, wT1);
    load_wf(wt + S_W2E1 * 8192, ft, l15, quad, wE2);
    __syncthreads();

    // residual e1 (own cells of pE) — valid now; t1 phase writes pH only.
    short4v rh[4], rl[4];
#pragma unroll
    for (int et = 0; et < 4; ++et) {
        const int e = et * 16 + l15;
        rh[et] = *(const short4v*)(pEhi + e * LDK + f0);
        rl[et] = *(const short4v*)(pElo + e * LDK + f0);
    }

    f32x4 acc[4];

    // t1 = relu(e1 @ W1e + Ps[src] + Pd[dst] + pb1) -> pH
    {
        set_zero(acc);
        gemm_planes(pEhi, pElo, wT1, l15, quad, acc);
        const float4 b4 = *(const float4*)(pb1 + f0);
#pragma unroll
        for (int et = 0; et < 4; ++et) {
            acc[et][0] = fmaxf(acc[et][0] + ps[et].x + pd[et].x + b4.x, 0.f);
            acc[et][1] = fmaxf(acc[et][1] + ps[et].y + pd[et].y + b4.y, 0.f);
            acc[et][2] = fmaxf(acc[et][2] + ps[et].z + pd[et].z + b4.z, 0.f);
            acc[et][3] = fmaxf(acc[et][3] + ps[et].w + pd[et].w + b4.w, 0.f);
        }
        store_split_planes(pHhi, pHlo, acc, l15, f0);
    }
    __syncthreads();

    // e2 = e1(regs residual) + t1 @ W2e + pb2 -> pE
    {
        set_zero(acc);
        gemm_planes(pHhi, pHlo, wE2, l15, quad, acc);
        const float4 b4 = *(const float4*)(pb2 + f0);
#pragma unroll
        for (int et = 0; et < 4; ++et) {
            const int e = et * 16 + l15;
            acc[et][0] += bf2f((unsigned short)rh[et][0]) + bf2f((unsigned short)rl[et][0]) + b4.x;
            acc[et][1] += bf2f((unsigned short)rh[et][1]) + bf2f((unsigned short)rl[et][1]) + b4.y;
            acc[et][2] += bf2f((unsigned short)rh[et][2]) + bf2f((unsigned short)rl[et][2]) + b4.z;
            acc[et][3] += bf2f((unsigned short)rh[et][3]) + bf2f((unsigned short)rl[et][3]) + b4.w;
            store_row4(pEhi, pElo, acc[et], e, f0);   // own cells, same thread
        }
    }
    __syncthreads();

    // fused aggregation: agg[dst] += e2
    segsum_atomic(pEhi, pElo, sDst, t, agg);
}

// ---------------- K3: node update l0 + layer-1 projections (+ agg self-zero) -----

__global__ __launch_bounds__(256, 4) void k_node_l0(
    float* x_h, float* agg, const unsigned short* __restrict__ wt,
    const float* __restrict__ nb1, const float* __restrict__ nb2,
    float* Ps, float* __restrict__ Pd)
{
    __shared__ unsigned short pXhi[EPB * LDK], pXlo[EPB * LDK];
    __shared__ unsigned short pAhi[EPB * LDK], pAlo[EPB * LDK];

    const int t = threadIdx.x;
    const int lane = t & 63, ft = t >> 6;
    const int quad = lane >> 4, l15 = lane & 15;
    const int f0 = ft * 16 + quad * 4;
    const int nodeBase = blockIdx.x * 64;
    const int nValid = min(64, NN - nodeBase);

    // hoist first-phase weight sets (overlap with staging)
    short8 wNX[2][2], wNA[2][2];
    load_wf(wt + S_W1NX0 * 8192, ft, l15, quad, wNX);
    load_wf(wt + S_W1NA0 * 8192, ft, l15, quad, wNA);

    stage_split64(pXhi, pXlo, x_h, nodeBase, t, nValid);
    stage_split64(pAhi, pAlo, agg, nodeBase, t, nValid);
    __syncthreads();

    // zero own agg slice for layer-1 (replaces memset#2; reads done above)
    {
        const uint4 z4 = {0u, 0u, 0u, 0u};
        uint4* ag = (uint4*)(agg + (size_t)nodeBase * HH);
#pragma unroll
        for (int j = 0; j < 4; ++j) {
            const int di = t + j * 256;
            if (nodeBase + (di >> 4) < NN) ag[di] = z4;
        }
    }

    f32x4 acc[4];

    // t1 = relu(x_h @ W1x + agg @ W1a + nb1)
    {
        set_bias(acc, nb1, f0);
        gemm_planes(pXhi, pXlo, wNX, l15, quad, acc);
        gemm_planes(pAhi, pAlo, wNA, l15, quad, acc);
        relu4(acc);
    }
    __syncthreads();                       // pA reads complete
    store_split_planes(pAhi, pAlo, acc, l15, f0);   // t1 -> pA
    __syncthreads();

    // x_h1 = x_h + t1 @ W2n + nb2 -> global + pX
    {
        short8 w[2][2];
        load_wf(wt + S_W2N0 * 8192, ft, l15, quad, w);
        set_bias(acc, nb2, f0);
        gemm_planes(pAhi, pAlo, w, l15, quad, acc);
#pragma unroll
        for (int et = 0; et < 4; ++et) {
            const int r = et * 16 + l15;
            if (r < nValid) {
                const size_t gi = (size_t)(nodeBase + r) * HH + f0;
                const float4 xr = *(const float4*)(x_h + gi);
                acc[et][0] += xr.x; acc[et][1] += xr.y;
                acc[et][2] += xr.z; acc[et][3] += xr.w;
                float4 v = make_float4(acc[et][0], acc[et][1], acc[et][2], acc[et][3]);
                *(float4*)(x_h + gi) = v;
            }
        }
        store_split_planes(pXhi, pXlo, acc, l15, f0);
    }
    __syncthreads();

    // Ps1 = x_h1 @ W1s(l1)
    {
        short8 w[2][2];
        load_wf(wt + S_W1S1 * 8192, ft, l15, quad, w);
        set_zero(acc);
        gemm_planes(pXhi, pXlo, w, l15, quad, acc);
#pragma unroll
        for (int et = 0; et < 4; ++et) {
            const int r = et * 16 + l15;
            if (r < nValid) {
                float4 v = make_float4(acc[et][0], acc[et][1], acc[et][2], acc[et][3]);
                *(float4*)(Ps + (size_t)(nodeBase + r) * HH + f0) = v;
            }
        }
    }
    // Pd1 = x_h1 @ W1d(l1)
    {
        short8 w[2][2];
        load_wf(wt + S_W1D1 * 8192, ft, l15, quad, w);
        set_zero(acc);
        gemm_planes(pXhi, pXlo, w, l15, quad, acc);
#pragma unroll
        for (int et = 0; et < 4; ++et) {
            const int r = et * 16 + l15;
            if (r < nValid) {
                float4 v = make_float4(acc[et][0], acc[et][1], acc[et][2], acc[et][3]);
                *(float4*)(Pd + (size_t)(nodeBase + r) * HH + f0) = v;
            }
        }
    }
}

// ---------------- K5: node update l1 + decoder ----------------

__global__ __launch_bounds__(256, 4) void k_node_l1_dec(
    const float* x_h, const float* agg, const unsigned short* __restrict__ wt,
    const float* __restrict__ nb1, const float* __restrict__ nb2,
    const float* __restrict__ db1, const float* __restrict__ dw2,
    const float* __restrict__ db2, float* __restrict__ out)
{
    __shared__ unsigned short pXhi[EPB * LDK], pXlo[EPB * LDK];
    __shared__ unsigned short pAhi[EPB * LDK], pAlo[EPB * LDK];
    __shared__ float sW2[64 * 6];

    const int t = threadIdx.x;
    const int lane = t & 63, ft = t >> 6;
    const int quad = lane >> 4, l15 = lane & 15;
    const int f0 = ft * 16 + quad * 4;
    const int nodeBase = blockIdx.x * 64;
    const int nValid = min(64, NN - nodeBase);

    // hoist first-phase weight sets (overlap with staging)
    short8 wNX[2][2], wNA[2][2];
    load_wf(wt + S_W1NX1 * 8192, ft, l15, quad, wNX);
    load_wf(wt + S_W1NA1 * 8192, ft, l15, quad, wNA);

    stage_split64(pXhi, pXlo, x_h, nodeBase, t, nValid);
    stage_split64(pAhi, pAlo, agg, nodeBase, t, nValid);
    if (t < 192) {
        sW2[t] = dw2[t];
        sW2[t + 192] = dw2[t + 192];
    }
    __syncthreads();

    f32x4 acc[4];

    // t1 = relu(x_h @ W1x + agg @ W1a + nb1)
    {
        set_bias(acc, nb1, f0);
        gemm_planes(pXhi, pXlo, wNX, l15, quad, acc);
        gemm_planes(pAhi, pAlo, wNA, l15, quad, acc);
        relu4(acc);
    }
    __syncthreads();
    store_split_planes(pAhi, pAlo, acc, l15, f0);   // t1 -> pA
    __syncthreads();

    // x_h2 = x_h + t1 @ W2n + nb2 -> pX (no global writeback needed)
    {
        short8 w[2][2];
        load_wf(wt + S_W2N1 * 8192, ft, l15, quad, w);
        set_bias(acc, nb2, f0);
        gemm_planes(pAhi, pAlo, w, l15, quad, acc);
#pragma unroll
        for (int et = 0; et < 4; ++et) {
            const int r = et * 16 + l15;
            if (r < nValid) {
                const float4 xr = *(const float4*)(x_h + (size_t)(nodeBase + r) * HH + f0);
                acc[et][0] += xr.x; acc[et][1] += xr.y;
                acc[et][2] += xr.z; acc[et][3] += xr.w;
            }
        }
        store_split_planes(pXhi, pXlo, acc, l15, f0);
    }
    __syncthreads();

    // d1 = relu(x_h2 @ dec_w1 + db1) -> pA
    {
        short8 w[2][2];
        load_wf(wt + S_DW1 * 8192, ft, l15, quad, w);
        set_bias(acc, db1, f0);
        gemm_planes(pXhi, pXlo, w, l15, quad, acc);
        relu4(acc);
        store_split_planes(pAhi, pAlo, acc, l15, f0);
    }
    __syncthreads();

    // out = d1 @ dec_w2 + db2  (64 nodes x 6)
    if (t < 64 && t < nValid) {
        float o[6];
#pragma unroll
        for (int c = 0; c < 6; ++c) o[c] = db2[c];
#pragma unroll 8
        for (int k = 0; k < 64; ++k) {
            const float a = bf2f(pAhi[t * LDK + k]) + bf2f(pAlo[t * LDK + k]);
#pragma unroll
            for (int c = 0; c < 6; ++c) o[c] = fmaf(a, sW2[k * 6 + c], o[c]);
        }
        float* op = out + (size_t)(nodeBase + t) * 6;
#pragma unroll
        for (int c = 0; c < 6; ++c) op[c] = o[c];
    }
}

// ---------------- launcher ----------------

extern "C" void kernel_launch(void* const* d_in, const int* in_sizes, int n_in,
                              void* d_out, int out_size, void* d_ws, size_t ws_size,
                              hipStream_t stream) {
    const float* x        = (const float*)d_in[0];
    const float* eattr    = (const float*)d_in[1];
    const int*   eidx     = (const int*)d_in[2];
    const float* enc_n_w1 = (const float*)d_in[3];
    const float* enc_n_b1 = (const float*)d_in[4];
    const float* enc_n_w2 = (const float*)d_in[5];
    const float* enc_n_b2 = (const float*)d_in[6];
    const float* enc_e_w1 = (const float*)d_in[7];
    const float* enc_e_b1 = (const float*)d_in[8];
    const float* enc_e_w2 = (const float*)d_in[9];
    const float* enc_e_b2 = (const float*)d_in[10];
    const float* pe_w1    = (const float*)d_in[11];  // [2,192,64]
    const float* pe_b1    = (const float*)d_in[12];  // [2,64]
    const float* pe_w2    = (const float*)d_in[13];  // [2,64,64]
    const float* pe_b2    = (const float*)d_in[14];  // [2,64]
    const float* pn_w1    = (const float*)d_in[15];  // [2,128,64]
    const float* pn_b1    = (const float*)d_in[16];
    const float* pn_w2    = (const float*)d_in[17];  // [2,64,64]
    const float* pn_b2    = (const float*)d_in[18];
    const float* dw1      = (const float*)d_in[19];
    const float* db1      = (const float*)d_in[20];
    const float* dw2      = (const float*)d_in[21];
    const float* db2      = (const float*)d_in[22];
    float* out = (float*)d_out;

    // ws: x_h | Ps | Pd | agg | epkHi|epkLo | sd(int2) | csr | off | deg | wt
    const size_t NNHH = (size_t)NN * HH;
    float* ws  = (float*)d_ws;
    float* x_h = ws;
    float* Ps  = ws + NNHH;
    float* Pd  = ws + 2 * NNHH;
    float* agg = ws + 3 * NNHH;
    unsigned short* epkHi = (unsigned short*)(ws + 4 * NNHH);   // EE*HH ushorts
    unsigned short* epkLo = epkHi + (size_t)EE * HH;            // EE*HH ushorts
    int2* sd    = (int2*)(epkLo + (size_t)EE * HH);             // EE int2 (src,dst)
    int* csr    = (int*)(sd + EE);                              // EE
    unsigned* off = (unsigned*)(csr + EE);                      // NN+4 (padded)
    unsigned* deg = off + (NN + 4);                             // NN, reused as cursor
    unsigned short* wt = (unsigned short*)(deg + NN);           // WT_USHORTS (16B-aligned)
    const float* fb = (const float*)(wt + FB_OFF);              // fused biases

    const int nodeBlocks = (NN + 63) / 64;   // 782
    const int edgeBlocks = EE / EPB;         // 12500
    const int eScal      = (EE + 255) / 256; // 3125 (= FILL_BLOCKS)
    const int convBlocks = (73728 + 3 * 4096 + 192 + NN + 255) / 256;  // 533

    k_conv_w<<<convBlocks, 256, 0, stream>>>(
        enc_n_w1, enc_n_w2, enc_e_w1, enc_e_w2,
        pe_w1, pe_w2, pn_w1, pn_w2, dw1,
        enc_n_b2, enc_e_b2, wt, deg);

    k_deg<<<eScal, 256, 0, stream>>>(eidx, deg);
    k_scan<<<1, 1024, 0, stream>>>(deg, off);

    k_fill_encode<<<FILL_BLOCKS + nodeBlocks, 256, 0, stream>>>(
        eidx, deg, csr, sd,
        x, wt, fb, enc_n_b1, enc_n_b2, x_h, Ps, Pd, agg);

    k_edge_l0<<<edgeBlocks, 256, 0, stream>>>(
        eattr, csr, sd, Ps, Pd,
        enc_e_w1, enc_e_b1, enc_e_b2, wt, fb, pe_b1, pe_b2, epkHi, epkLo, agg);

    k_node_l0<<<nodeBlocks, 256, 0, stream>>>(
        x_h, agg, wt, pn_b1, pn_b2, Ps, Pd);

    k_edge_l1<<<edgeBlocks, 256, 0, stream>>>(
        sd, Ps, Pd, wt, pe_b1 + 64, pe_b2 + 64, epkHi, epkLo, agg);

    k_node_l1_dec<<<nodeBlocks, 256, 0, stream>>>(
        x_h, agg, wt, pn_b1 + 64, pn_b2 + 64,
        db1, dw2, db2, out);
}

// Round 16
// 524.213 us; speedup vs baseline: 1.0174x; 1.0174x over previous
//
#include <hip/hip_runtime.h>

// GNN: N=50000 nodes, E=800000 edges, H=64, L=2.
// R22 = R19 verbatim (measured best, 531.6us, absmax 2.441e-4).
// R20 (XCD swizzle) was neutral; R21 (sorted-eattr pre-gather) exceeded the
// ~256MiB workspace and crashed (276MB > 268.4MB). Locking in the best.
// Session: 694.7 -> 531.6us via: fused agg + prefetch (R8), cvt_pk splits
// (R11+), phase fusion via precomputed weight products (R13), dispatch/memset
// elimination + vectorized scan (R14), split-plane epk (R16), fp32 K=4
// encoder phase (R17), weight hoisting (R18), NT epk + int2 CSR (R19).
// Pipeline: conv_w(+fuse,+deg0) | deg | scan | fill+encode(+agg0) |
//           edge_l0(+agg) | node_l0(+agg0) | edge_l1(+agg) | node_l1+dec.

#define NN 50000
#define EE 800000
#define HH 64
#define LDK 72   // bf16 plane leading dim (144 B row)
#define EPB 64   // rows per block

typedef short short8 __attribute__((ext_vector_type(8)));
typedef short short4v __attribute__((ext_vector_type(4)));
typedef float f32x4 __attribute__((ext_vector_type(4)));
typedef unsigned uint4v __attribute__((ext_vector_type(4)));

#define MFMA __builtin_amdgcn_mfma_f32_16x16x32_bf16

// wt slots (each 8192 ushorts: 4096 hi + 4096 lo, layout [f][k])
#define S_WE2   0
#define S_W1E0  1
#define S_W2E0  2
#define S_W1E1  3
#define S_W2E1  4
#define S_WN2   5
#define S_W1S0  6
#define S_W1D0  7
#define S_W1S1  8
#define S_W1D1  9
#define S_W1NX0 10
#define S_W1NA0 11
#define S_W2N0  12
#define S_W1NX1 13
#define S_W1NA1 14
#define S_W2N1  15
#define S_DW1   16
#define S_WE21  17  // We2(l0e) @ W1e(l0)
#define S_WNS0  18  // wn2 @ W1s(l0)
#define S_WND0  19  // wn2 @ W1d(l0)
#define OFF_WE1 (20*8192)          // [f][32], K=4 padded (legacy, unused by edge_l0 now)
#define OFF_WN1 (20*8192+4096)     // [f][32], K=8 padded
#define FB_OFF  (20*8192+8192)     // ushort offset of float fused biases
// fb floats: [0..63]=be2@W1e, [64..127]=bn2@W1s0, [128..191]=bn2@W1d0
#define WT_USHORTS (20*8192+8192+384)

// ---------------- bf16 helpers ----------------

__device__ __forceinline__ void split2(float x, unsigned short& h, unsigned short& l) {
    union { float f; unsigned u; } a, hf, b;
    a.f = x;
    const unsigned hb = (a.u + 0x7FFFu + ((a.u >> 16) & 1u)) >> 16;  // RNE hi
    hf.u = hb << 16;
    b.f = x - hf.f;                  // exact
    h = (unsigned short)hb;
    l = (unsigned short)(b.u >> 16); // truncated lo: err <= 2^-16 |x|
}

__device__ __forceinline__ float bf2f(unsigned short s) {
    union { unsigned u; float f; } a; a.u = ((unsigned)s) << 16; return a.f;
}

// packed split (numerics == split2, verified R11-R19 absmax-identical)
__device__ __forceinline__ unsigned cvtpk_bf16(float a, float b) {
    unsigned r;
    asm("v_cvt_pk_bf16_f32 %0, %1, %2" : "=v"(r) : "v"(a), "v"(b));
    return r;
}
__device__ __forceinline__ void split_pair(float x0, float x1, unsigned& hw, unsigned& lw) {
    hw = cvtpk_bf16(x0, x1);
    union { unsigned u; float f; } h0, h1, r0, r1;
    h0.u = hw << 16;
    h1.u = hw & 0xFFFF0000u;
    r0.f = x0 - h0.f;
    r1.f = x1 - h1.f;
    lw = (r0.u >> 16) | (r1.u & 0xFFFF0000u);
}

// non-temporal 16B helpers (bypass L2 allocation for streamed epk)
__device__ __forceinline__ void nt_store16(void* p, const void* v) {
    __builtin_nontemporal_store(*(const uint4v*)v, (uint4v*)p);
}
__device__ __forceinline__ void nt_load16(void* dst, const void* p) {
    *(uint4v*)dst = __builtin_nontemporal_load((const uint4v*)p);
}

// A-frags for one 16-feature slice of a 64x64 weight: [chunk][plane]
__device__ __forceinline__ void load_wf(const unsigned short* __restrict__ wm,
                                        int ft, int l15, int quad, short8 (&w)[2][2]) {
#pragma unroll
    for (int c = 0; c < 2; ++c) {
        const int el = (ft * 16 + l15) * 64 + c * 32 + quad * 8;
        w[c][0] = *(const short8*)(wm + el);
        w[c][1] = *(const short8*)(wm + 4096 + el);
    }
}

// D += Ah*Bh + Al*Bh + Ah*Bl over K=64 (2 chunks)
__device__ __forceinline__ f32x4 chain6(const short8 (&w)[2][2],
                                        short8 bh0, short8 bh1,
                                        short8 bl0, short8 bl1, f32x4 a) {
    a = MFMA(w[0][0], bh0, a, 0, 0, 0);
    a = MFMA(w[1][0], bh1, a, 0, 0, 0);
    a = MFMA(w[0][1], bh0, a, 0, 0, 0);
    a = MFMA(w[1][1], bh1, a, 0, 0, 0);
    a = MFMA(w[0][0], bl0, a, 0, 0, 0);
    a = MFMA(w[1][0], bl1, a, 0, 0, 0);
    return a;
}

// one row-tile GEMM step: acc += W @ B(row e)
__device__ __forceinline__ void gemm_tile(const unsigned short* pHi, const unsigned short* pLo,
                                          const short8 (&w)[2][2], int e, int quad, f32x4& a) {
    const short8 bh0 = *(const short8*)(pHi + e * LDK + quad * 8);
    const short8 bh1 = *(const short8*)(pHi + e * LDK + 32 + quad * 8);
    const short8 bl0 = *(const short8*)(pLo + e * LDK + quad * 8);
    const short8 bl1 = *(const short8*)(pLo + e * LDK + 32 + quad * 8);
    a = chain6(w, bh0, bh1, bl0, bl1, a);
}

// store 4 feats of row e via packed cvt split
__device__ __forceinline__ void store_row4(unsigned short* pHi, unsigned short* pLo,
                                           const f32x4& a, int e, int f0) {
    unsigned hw0, lw0, hw1, lw1;
    split_pair(a[0], a[1], hw0, lw0);
    split_pair(a[2], a[3], hw1, lw1);
    uint2 hv; hv.x = hw0; hv.y = hw1;
    uint2 lv; lv.x = lw0; lv.y = lw1;
    *(uint2*)(pHi + e * LDK + f0) = hv;
    *(uint2*)(pLo + e * LDK + f0) = lv;
}

// ======== 4-tile helpers (256 thr) ========

__device__ __forceinline__ void gemm_planes(const unsigned short* pHi, const unsigned short* pLo,
                                            const short8 (&w)[2][2], int l15, int quad,
                                            f32x4 (&acc)[4]) {
#pragma unroll
    for (int et = 0; et < 4; ++et) {
        const int e = et * 16 + l15;
        gemm_tile(pHi, pLo, w, e, quad, acc[et]);
    }
}

__device__ __forceinline__ void set_bias(f32x4 (&acc)[4], const float* __restrict__ b, int f0) {
    const float4 b4 = *(const float4*)(b + f0);
#pragma unroll
    for (int et = 0; et < 4; ++et) {
        acc[et][0] = b4.x; acc[et][1] = b4.y; acc[et][2] = b4.z; acc[et][3] = b4.w;
    }
}

__device__ __forceinline__ void set_zero(f32x4 (&acc)[4]) {
#pragma unroll
    for (int et = 0; et < 4; ++et)
#pragma unroll
        for (int r = 0; r < 4; ++r) acc[et][r] = 0.f;
}

__device__ __forceinline__ void relu4(f32x4 (&acc)[4]) {
#pragma unroll
    for (int et = 0; et < 4; ++et)
#pragma unroll
        for (int r = 0; r < 4; ++r) acc[et][r] = fmaxf(acc[et][r], 0.f);
}

__device__ __forceinline__ void store_split_planes(unsigned short* pHi, unsigned short* pLo,
                                                   const f32x4 (&acc)[4], int l15, int f0) {
#pragma unroll
    for (int et = 0; et < 4; ++et) store_row4(pHi, pLo, acc[et], et * 16 + l15, f0);
}

// stage fp32 [64][64] tile -> split hi/lo planes; invalid rows zero
__device__ __forceinline__ void stage_split64(unsigned short* pHi, unsigned short* pLo,
                                              const float* g, long rowBase, int t, int nValid) {
    const int row = t >> 2, q = t & 3;
    const bool valid = row < nValid;
#pragma unroll
    for (int i = 0; i < 4; ++i) {
        const int col = q * 16 + i * 4;
        float4 v = make_float4(0.f, 0.f, 0.f, 0.f);
        if (valid) v = *(const float4*)(g + (size_t)(rowBase + row) * HH + col);
        unsigned hw0, lw0, hw1, lw1;
        split_pair(v.x, v.y, hw0, lw0);
        split_pair(v.z, v.w, hw1, lw1);
        uint2 hv; hv.x = hw0; hv.y = hw1;
        uint2 lv; lv.x = lw0; lv.y = lw1;
        *(uint2*)(pHi + row * LDK + col) = hv;
        *(uint2*)(pLo + row * LDK + col) = lv;
    }
}

// in-LDS segment sum over dst-sorted rows + atomic scatter (64 rows, 4 waves)
__device__ __forceinline__ void segsum_atomic(const unsigned short* pHi, const unsigned short* pLo,
                                              const int* sDst, int t,
                                              float* __restrict__ agg) {
    const int f = t & 63, c0 = (t >> 6) * 16;
    float s = 0.f;
    int d = sDst[c0];
#pragma unroll
    for (int i = 0; i < 16; ++i) {
        const int r = c0 + i;
        s += bf2f(pHi[r * LDK + f]) + bf2f(pLo[r * LDK + f]);
        const int dn = (i == 15) ? -1 : sDst[r + 1];
        if (dn != d) {
            atomicAdd(&agg[(size_t)d * HH + f], s);
            s = 0.f; d = dn;
        }
    }
}

// ---------------- setup: weights + fused products + deg zero (one kernel) -------

__global__ void k_conv_w(const float* __restrict__ enc_n_w1, const float* __restrict__ enc_n_w2,
                         const float* __restrict__ enc_e_w1, const float* __restrict__ enc_e_w2,
                         const float* __restrict__ pe_w1, const float* __restrict__ pe_w2,
                         const float* __restrict__ pn_w1, const float* __restrict__ pn_w2,
                         const float* __restrict__ dw1,
                         const float* __restrict__ enc_n_b2, const float* __restrict__ enc_e_b2,
                         unsigned short* __restrict__ wt, unsigned* __restrict__ deg)
{
    const int i = blockIdx.x * 256 + threadIdx.x;
    if (i < 17 * 4096) {
        const int m = i >> 12, r = i & 4095;
        const int f = r & 63, k = r >> 6;
        const float* W;
        switch (m) {
            case S_WE2:   W = enc_e_w2; break;
            case S_W1E0:  W = pe_w1; break;
            case S_W2E0:  W = pe_w2; break;
            case S_W1E1:  W = pe_w1 + 192 * 64; break;
            case S_W2E1:  W = pe_w2 + 64 * 64; break;
            case S_WN2:   W = enc_n_w2; break;
            case S_W1S0:  W = pe_w1 + 64 * 64; break;
            case S_W1D0:  W = pe_w1 + 128 * 64; break;
            case S_W1S1:  W = pe_w1 + 192 * 64 + 64 * 64; break;
            case S_W1D1:  W = pe_w1 + 192 * 64 + 128 * 64; break;
            case S_W1NX0: W = pn_w1; break;
            case S_W1NA0: W = pn_w1 + 64 * 64; break;
            case S_W2N0:  W = pn_w2; break;
            case S_W1NX1: W = pn_w1 + 128 * 64; break;
            case S_W1NA1: W = pn_w1 + 128 * 64 + 64 * 64; break;
            case S_W2N1:  W = pn_w2 + 64 * 64; break;
            default:      W = dw1; break;
        }
        unsigned short h, l; split2(W[r], h, l);    // W[k*64+f]
        wt[m * 8192 + f * 64 + k] = h;
        wt[m * 8192 + 4096 + f * 64 + k] = l;
    } else if (i < 17 * 4096 + 2048) {
        const int r = i - 17 * 4096, f = r >> 5, k = r & 31;
        const float v = (k < 4) ? enc_e_w1[k * 64 + f] : 0.f;
        unsigned short h, l; split2(v, h, l);
        wt[OFF_WE1 + f * 32 + k] = h;
        wt[OFF_WE1 + 2048 + f * 32 + k] = l;
    } else if (i < 17 * 4096 + 4096) {
        const int r = i - 17 * 4096 - 2048, f = r >> 5, k = r & 31;
        const float v = (k < 8) ? enc_n_w1[k * 64 + f] : 0.f;
        unsigned short h, l; split2(v, h, l);
        wt[OFF_WN1 + f * 32 + k] = h;
        wt[OFF_WN1 + 2048 + f * 32 + k] = l;
    } else if (i < 73728 + 3 * 4096) {
        // fused weight products (fp32)
        const int r = i - 73728;
        const int m = r >> 12, rr = r & 4095;
        const int g = rr & 63, j = rr >> 6;
        const float* A = (m == 0) ? enc_e_w2 : enc_n_w2;
        const float* B = pe_w1 + m * 64 * 64;   // m0: e-slice, m1: src, m2: dst
        float s = 0.f;
#pragma unroll 8
        for (int f = 0; f < 64; ++f) s += A[j * 64 + f] * B[f * 64 + g];
        unsigned short h, l; split2(s, h, l);
        wt[(S_WE21 + m) * 8192 + g * 64 + j] = h;
        wt[(S_WE21 + m) * 8192 + 4096 + g * 64 + j] = l;
    } else if (i < 73728 + 3 * 4096 + 192) {
        const int r = i - 73728 - 3 * 4096;
        const int m = r >> 6, g = r & 63;
        const float* bb = (m == 0) ? enc_e_b2 : enc_n_b2;
        const float* B = pe_w1 + m * 64 * 64;
        float s = 0.f;
#pragma unroll 8
        for (int f = 0; f < 64; ++f) s += bb[f] * B[f * 64 + g];
        float* fbp = (float*)(wt + FB_OFF);
        fbp[m * 64 + g] = s;
    } else if (i < 73728 + 3 * 4096 + 192 + NN) {
        deg[i - (73728 + 3 * 4096 + 192)] = 0u;   // replaces memset(deg)
    }
}

// ---------------- CSR build ----------------

__global__ void k_deg(const int* __restrict__ eidx, unsigned* __restrict__ deg) {
    const int e = blockIdx.x * 256 + threadIdx.x;
    if (e < EE) atomicAdd(&deg[eidx[EE + e]], 1u);
}

__global__ __launch_bounds__(1024) void k_scan(unsigned* deg, unsigned* __restrict__ off) {
    __shared__ unsigned part[1024];
    const int t = threadIdx.x;
    const int CH = 52;                    // 1024*52 = 53248 >= NN; 52*4B 16B-aligned
    const int s = t * CH;
    unsigned v[52];
    unsigned sum = 0;
#pragma unroll
    for (int j = 0; j < 13; ++j) {
        const int i = s + j * 4;
        uint4 u = {0u, 0u, 0u, 0u};
        if (i + 3 < NN) {
            u = *(const uint4*)(deg + i);
        } else {
            if (i < NN)     u.x = deg[i];
            if (i + 1 < NN) u.y = deg[i + 1];
            if (i + 2 < NN) u.z = deg[i + 2];
            if (i + 3 < NN) u.w = deg[i + 3];
        }
        v[j * 4] = u.x; v[j * 4 + 1] = u.y; v[j * 4 + 2] = u.z; v[j * 4 + 3] = u.w;
        sum += u.x + u.y + u.z + u.w;
    }
    part[t] = sum;
    __syncthreads();
    for (int d = 1; d < 1024; d <<= 1) {
        unsigned p = (t >= d) ? part[t - d] : 0u;
        __syncthreads();
        if (t >= d) part[t] += p;
        __syncthreads();
    }
    unsigned base = (t > 0) ? part[t - 1] : 0u;
#pragma unroll
    for (int j = 0; j < 13; ++j) {
        const int i = s + j * 4;
        uint4 o;
        o.x = base; base += v[j * 4];
        o.y = base; base += v[j * 4 + 1];
        o.z = base; base += v[j * 4 + 2];
        o.w = base; base += v[j * 4 + 3];
        if (i + 3 < NN) {
            *(uint4*)(off + i) = o;
            *(uint4*)(deg + i) = o;       // reuse as fill cursor
        } else {
            if (i < NN)     { off[i] = o.x;     deg[i] = o.x; }
            if (i + 1 < NN) { off[i + 1] = o.y; deg[i + 1] = o.y; }
            if (i + 2 < NN) { off[i + 2] = o.z; deg[i + 2] = o.z; }
            if (i + 3 < NN) { off[i + 3] = o.w; deg[i + 3] = o.w; }
        }
    }
    if (t == 1023) off[NN] = part[1023];
}

// ---------------- K1': CSR fill + node encoder (combined grid) ----------------
// blocks [0, 3125): fill; blocks [3125, 3125+782): encode (+ zero agg slice).

#define FILL_BLOCKS 3125

__global__ __launch_bounds__(256, 4) void k_fill_encode(
    const int* __restrict__ eidx, unsigned* __restrict__ cur,
    int* __restrict__ csr, int2* __restrict__ sd,
    const float* __restrict__ x, const unsigned short* __restrict__ wt,
    const float* __restrict__ fb,
    const float* __restrict__ bn1, const float* __restrict__ bn2,
    float* __restrict__ x_h, float* __restrict__ Ps, float* __restrict__ Pd,
    float* __restrict__ agg)
{
    __shared__ unsigned short pXhi[EPB * LDK], pXlo[EPB * LDK];
    __shared__ unsigned short pHhi[EPB * LDK], pHlo[EPB * LDK];

    if (blockIdx.x < FILL_BLOCKS) {
        const int e = blockIdx.x * 256 + threadIdx.x;
        if (e < EE) {
            const int s = eidx[e];
            const int d = eidx[EE + e];
            const unsigned p = atomicAdd(&cur[d], 1u);
            csr[p] = e;
            sd[p] = make_int2(s, d);
        }
        return;
    }

    const int t = threadIdx.x;
    const int lane = t & 63, ft = t >> 6;
    const int quad = lane >> 4, l15 = lane & 15;
    const int f0 = ft * 16 + quad * 4;
    const int nodeBase = (blockIdx.x - FILL_BLOCKS) * 64;
    const int nValid = min(64, NN - nodeBase);

    // zero agg slice (replaces memset#1; consumed by edge_l0 later)
    {
        const uint4 z4 = {0u, 0u, 0u, 0u};
        uint4* ag = (uint4*)(agg + (size_t)nodeBase * HH);
#pragma unroll
        for (int j = 0; j < 4; ++j) {
            const int di = t + j * 256;             // uint4 idx 0..1023
            if (nodeBase + (di >> 4) < NN) ag[di] = z4;
        }
    }

    // hoist phase1 weight frags (overlap with x staging)
    short8 wN1a, wN1b;
    {
        const int el = (ft * 16 + l15) * 32 + quad * 8;
        wN1a = *(const short8*)(wt + OFF_WN1 + el);
        wN1b = *(const short8*)(wt + OFF_WN1 + 2048 + el);
    }

    // stage x (8 cols) padded to 32
    {
        const int row = t >> 2, q = t & 3;
        if (q == 0) {
            float4 a0 = make_float4(0.f, 0.f, 0.f, 0.f), a1 = a0;
            if (row < nValid) {
                a0 = *(const float4*)(x + (size_t)(nodeBase + row) * 8);
                a1 = *(const float4*)(x + (size_t)(nodeBase + row) * 8 + 4);
            }
            unsigned hw0, lw0, hw1, lw1, hw2, lw2, hw3, lw3;
            split_pair(a0.x, a0.y, hw0, lw0);
            split_pair(a0.z, a0.w, hw1, lw1);
            split_pair(a1.x, a1.y, hw2, lw2);
            split_pair(a1.z, a1.w, hw3, lw3);
            uint4 H; H.x = hw0; H.y = hw1; H.z = hw2; H.w = hw3;
            uint4 L; L.x = lw0; L.y = lw1; L.z = lw2; L.w = lw3;
            *(uint4*)(pXhi + row * LDK) = H;
            *(uint4*)(pXlo + row * LDK) = L;
        } else {
            const uint4 z = {0u, 0u, 0u, 0u};
            *(uint4*)(pXhi + row * LDK + q * 8) = z;
            *(uint4*)(pXlo + row * LDK + q * 8) = z;
        }
    }
    __syncthreads();

    f32x4 acc[4];

    // phase1: h1 = relu(x @ wn1 + bn1) -> pH
    {
        set_bias(acc, bn1, f0);
#pragma unroll
        for (int et = 0; et < 4; ++et) {
            const int e = et * 16 + l15;
            const short8 bh0 = *(const short8*)(pXhi + e * LDK + quad * 8);
            const short8 bl0 = *(const short8*)(pXlo + e * LDK + quad * 8);
            f32x4 a = acc[et];
            a = MFMA(wN1a, bh0, a, 0, 0, 0);
            a = MFMA(wN1b, bh0, a, 0, 0, 0);
            a = MFMA(wN1a, bl0, a, 0, 0, 0);
            acc[et] = a;
        }
        relu4(acc);
        store_split_planes(pHhi, pHlo, acc, l15, f0);
    }
    __syncthreads();

    // phase2' (fused, read-only on pH):
    // x_h = h1 @ wn2 + bn2
    {
        short8 w[2][2];
        load_wf(wt + S_WN2 * 8192, ft, l15, quad, w);
        set_bias(acc, bn2, f0);
        gemm_planes(pHhi, pHlo, w, l15, quad, acc);
#pragma unroll
        for (int et = 0; et < 4; ++et) {
            const int r = et * 16 + l15;
            if (r < nValid) {
                float4 v = make_float4(acc[et][0], acc[et][1], acc[et][2], acc[et][3]);
                *(float4*)(x_h + (size_t)(nodeBase + r) * HH + f0) = v;
            }
        }
    }
    // Ps = h1 @ (wn2*W1s0) + bn2@W1s0
    {
        short8 w[2][2];
        load_wf(wt + S_WNS0 * 8192, ft, l15, quad, w);
        set_bias(acc, fb + 64, f0);
        gemm_planes(pHhi, pHlo, w, l15, quad, acc);
#pragma unroll
        for (int et = 0; et < 4; ++et) {
            const int r = et * 16 + l15;
            if (r < nValid) {
                float4 v = make_float4(acc[et][0], acc[et][1], acc[et][2], acc[et][3]);
                *(float4*)(Ps + (size_t)(nodeBase + r) * HH + f0) = v;
            }
        }
    }
    // Pd = h1 @ (wn2*W1d0) + bn2@W1d0
    {
        short8 w[2][2];
        load_wf(wt + S_WND0 * 8192, ft, l15, quad, w);
        set_bias(acc, fb + 128, f0);
        gemm_planes(pHhi, pHlo, w, l15, quad, acc);
#pragma unroll
        for (int et = 0; et < 4; ++et) {
            const int r = et * 16 + l15;
            if (r < nValid) {
                float4 v = make_float4(acc[et][0], acc[et][1], acc[et][2], acc[et][3]);
                *(float4*)(Pd + (size_t)(nodeBase + r) * HH + f0) = v;
            }
        }
    }
}

// ---------------- K2: edge encoder + layer-0 edge MLP + fused agg ----------------
// phase1 fp32 VALU (K=4); weight frags hoisted; epk stored non-temporal.

__global__ __launch_bounds__(256, 4) void k_edge_l0(
    const float* __restrict__ eattr, const int* __restrict__ csr,
    const int2* __restrict__ sd,
    const float* __restrict__ Ps, const float* __restrict__ Pd,
    const float* __restrict__ we1, const float* __restrict__ be1,
    const float* __restrict__ be2,
    const unsigned short* __restrict__ wt, const float* __restrict__ fb,
    const float* __restrict__ pb1, const float* __restrict__ pb2,
    unsigned short* __restrict__ epkHi, unsigned short* __restrict__ epkLo,
    float* __restrict__ agg)
{
    __shared__ unsigned short pHhi[EPB * LDK], pHlo[EPB * LDK];
    __shared__ unsigned short pEhi[EPB * LDK], pElo[EPB * LDK];
    __shared__ int sDst[EPB];

    const int t = threadIdx.x;
    const int lane = t & 63, ft = t >> 6;
    const int quad = lane >> 4, l15 = lane & 15;
    const int f0 = ft * 16 + quad * 4;
    const long eBase = (long)blockIdx.x * EPB;

    int srcs[4], dsts[4];
    float4 ea[4];
#pragma unroll
    for (int et = 0; et < 4; ++et) {
        const long p = eBase + et * 16 + l15;
        const int2 v = sd[p];
        srcs[et] = v.x;
        dsts[et] = v.y;
        const int eid = csr[p];
        ea[et] = *(const float4*)(eattr + (size_t)eid * 4);
    }
    if (t < EPB) sDst[t] = sd[eBase + t].y;

    // prefetch Ps/Pd gathers (consumed in fused phase2')
    float4 ps[4], pd[4];
#pragma unroll
    for (int et = 0; et < 4; ++et) {
        ps[et] = *(const float4*)(Ps + (size_t)srcs[et] * HH + f0);
        pd[et] = *(const float4*)(Pd + (size_t)dsts[et] * HH + f0);
    }
    // hoist ALL weight frags (3 sets, overlap with the gathers above)
    short8 wE2[2][2], wE21[2][2], wW2[2][2];
    load_wf(wt + S_WE2 * 8192, ft, l15, quad, wE2);
    load_wf(wt + S_WE21 * 8192, ft, l15, quad, wE21);
    load_wf(wt + S_W2E0 * 8192, ft, l15, quad, wW2);

    f32x4 acc[4];

    // phase1 (fp32 VALU, K=4): h0 = relu(eattr @ We1 + be1) -> pE
    {
        const float4 w0 = *(const float4*)(we1 + 0 * HH + f0);
        const float4 w1 = *(const float4*)(we1 + 1 * HH + f0);
        const float4 w2 = *(const float4*)(we1 + 2 * HH + f0);
        const float4 w3 = *(const float4*)(we1 + 3 * HH + f0);
        const float4 b1 = *(const float4*)(be1 + f0);
#pragma unroll
        for (int et = 0; et < 4; ++et) {
            const int e = et * 16 + l15;
            f32x4 a;
            a[0] = fmaf(ea[et].x, w0.x, fmaf(ea[et].y, w1.x,
                   fmaf(ea[et].z, w2.x, fmaf(ea[et].w, w3.x, b1.x))));
            a[1] = fmaf(ea[et].x, w0.y, fmaf(ea[et].y, w1.y,
                   fmaf(ea[et].z, w2.y, fmaf(ea[et].w, w3.y, b1.y))));
            a[2] = fmaf(ea[et].x, w0.z, fmaf(ea[et].y, w1.z,
                   fmaf(ea[et].z, w2.z, fmaf(ea[et].w, w3.z, b1.z))));
            a[3] = fmaf(ea[et].x, w0.w, fmaf(ea[et].y, w1.w,
                   fmaf(ea[et].z, w2.w, fmaf(ea[et].w, w3.w, b1.w))));
#pragma unroll
            for (int r = 0; r < 4; ++r) a[r] = fmaxf(a[r], 0.f);
            store_row4(pEhi, pElo, a, e, f0);
        }
    }
    __syncthreads();

    // phase2' (fused, SINGLE LDS read of h0 per tile feeds BOTH chains):
    // e0 = h0 @ We2 + be2 (regs residual); t1 = relu(h0 @ WE21 + fb + pb1 + Ps + Pd) -> pH
    f32x4 e0s[4];
    {
        const float4 b2 = *(const float4*)(be2 + f0);
        const float4 fa = *(const float4*)(fb + f0);       // be2@W1e
        const float4 p1 = *(const float4*)(pb1 + f0);
        const float4 tb = make_float4(fa.x + p1.x, fa.y + p1.y,
                                      fa.z + p1.z, fa.w + p1.w);
#pragma unroll
        for (int et = 0; et < 4; ++et) {
            const int e = et * 16 + l15;
            const short8 bh0 = *(const short8*)(pEhi + e * LDK + quad * 8);
            const short8 bh1 = *(const short8*)(pEhi + e * LDK + 32 + quad * 8);
            const short8 bl0 = *(const short8*)(pElo + e * LDK + quad * 8);
            const short8 bl1 = *(const short8*)(pElo + e * LDK + 32 + quad * 8);
            f32x4 a; a[0] = b2.x; a[1] = b2.y; a[2] = b2.z; a[3] = b2.w;
            a = chain6(wE2, bh0, bh1, bl0, bl1, a);
            e0s[et] = a;
            f32x4 b = {0.f, 0.f, 0.f, 0.f};
            b = chain6(wE21, bh0, bh1, bl0, bl1, b);
            b[0] = fmaxf(b[0] + ps[et].x + pd[et].x + tb.x, 0.f);
            b[1] = fmaxf(b[1] + ps[et].y + pd[et].y + tb.y, 0.f);
            b[2] = fmaxf(b[2] + ps[et].z + pd[et].z + tb.z, 0.f);
            b[3] = fmaxf(b[3] + ps[et].w + pd[et].w + tb.w, 0.f);
            store_row4(pHhi, pHlo, b, e, f0);
        }
    }
    __syncthreads();

    // phase3': e1 = e0(regs) + t1 @ W2e + pb2 -> pE
    {
        set_zero(acc);
        gemm_planes(pHhi, pHlo, wW2, l15, quad, acc);
        const float4 b4 = *(const float4*)(pb2 + f0);
#pragma unroll
        for (int et = 0; et < 4; ++et) {
            acc[et][0] += e0s[et][0] + b4.x;
            acc[et][1] += e0s[et][1] + b4.y;
            acc[et][2] += e0s[et][2] + b4.z;
            acc[et][3] += e0s[et][3] + b4.w;
        }
        store_split_planes(pEhi, pElo, acc, l15, f0);
    }
    __syncthreads();

    // pack pE -> epk planes (pure uint4 copies, NON-TEMPORAL stores)
    {
        const int row = t >> 2, q = t & 3;
#pragma unroll
        for (int half = 0; half < 2; ++half) {
            const int lo = row * LDK + q * 8 + half * 32;
            const long go = (eBase + row) * HH + q * 8 + half * 32;
            uint4 hv = *(const uint4*)(pEhi + lo);
            uint4 lv = *(const uint4*)(pElo + lo);
            nt_store16(epkHi + go, &hv);
            nt_store16(epkLo + go, &lv);
        }
    }
    // fused aggregation: agg[dst] += e1
    segsum_atomic(pEhi, pElo, sDst, t, agg);
}

// ---------------- K4: layer-1 edge MLP + fused agg ----------------

__global__ __launch_bounds__(256, 4) void k_edge_l1(
    const int2* __restrict__ sd,
    const float* __restrict__ Ps, const float* __restrict__ Pd,
    const unsigned short* __restrict__ wt,
    const float* __restrict__ pb1, const float* __restrict__ pb2,
    const unsigned short* __restrict__ epkHi, const unsigned short* __restrict__ epkLo,
    float* __restrict__ agg)
{
    __shared__ unsigned short pEhi[EPB * LDK], pElo[EPB * LDK];
    __shared__ unsigned short pHhi[EPB * LDK], pHlo[EPB * LDK];
    __shared__ int sDst[EPB];

    const int t = threadIdx.x;
    const int lane = t & 63, ft = t >> 6;
    const int quad = lane >> 4, l15 = lane & 15;
    const int f0 = ft * 16 + quad * 4;
    const long eBase = (long)blockIdx.x * EPB;

    // load epk planes -> pE (pure uint4 copies, NON-TEMPORAL loads)
    {
        const int row = t >> 2, q = t & 3;
#pragma unroll
        for (int half = 0; half < 2; ++half) {
            const int lo = row * LDK + q * 8 + half * 32;
            const long go = (eBase + row) * HH + q * 8 + half * 32;
            uint4 hv, lv;
            nt_load16(&hv, epkHi + go);
            nt_load16(&lv, epkLo + go);
            *(uint4*)(pEhi + lo) = hv;
            *(uint4*)(pElo + lo) = lv;
        }
    }
    if (t < EPB) sDst[t] = sd[eBase + t].y;

    int srcs[4], dsts[4];
#pragma unroll
    for (int et = 0; et < 4; ++et) {
        const long p = eBase + et * 16 + l15;
        const int2 v = sd[p];
        srcs[et] = v.x;
        dsts[et] = v.y;
    }
    // prefetch Ps/Pd gathers (consumed in t1 phase)
    float4 ps[4], pd[4];
#pragma unroll
    for (int et = 0; et < 4; ++et) {
        ps[et] = *(const float4*)(Ps + (size_t)srcs[et] * HH + f0);
        pd[et] = *(const float4*)(Pd + (size_t)dsts[et] * HH + f0);
    }
    // hoist both weight sets (overlap with staging/gathers)
    short8 wT1[2][2], wE2[2][2];
    load_wf(wt + S_W1E1 * 8192, ft, l15, quad, wT1);
    load_wf(wt + S_W2E1 * 8192, ft, l15, quad, wE2);
    __syncthreads();

    // residual e1 (own cells of pE) — valid now; t1 phase writes pH only.
    short4v rh[4], rl[4];
#pragma unroll
    for (int et = 0; et < 4; ++et) {
        const int e = et * 16 + l15;
        rh[et] = *(const short4v*)(pEhi + e * LDK + f0);
        rl[et] = *(const short4v*)(pElo + e * LDK + f0);
    }

    f32x4 acc[4];

    // t1 = relu(e1 @ W1e + Ps[src] + Pd[dst] + pb1) -> pH
    {
        set_zero(acc);
        gemm_planes(pEhi, pElo, wT1, l15, quad, acc);
        const float4 b4 = *(const float4*)(pb1 + f0);
#pragma unroll
        for (int et = 0; et < 4; ++et) {
            acc[et][0] = fmaxf(acc[et][0] + ps[et].x + pd[et].x + b4.x, 0.f);
            acc[et][1] = fmaxf(acc[et][1] + ps[et].y + pd[et].y + b4.y, 0.f);
            acc[et][2] = fmaxf(acc[et][2] + ps[et].z + pd[et].z + b4.z, 0.f);
            acc[et][3] = fmaxf(acc[et][3] + ps[et].w + pd[et].w + b4.w, 0.f);
        }
        store_split_planes(pHhi, pHlo, acc, l15, f0);
    }
    __syncthreads();

    // e2 = e1(regs residual) + t1 @ W2e + pb2 -> pE
    {
        set_zero(acc);
        gemm_planes(pHhi, pHlo, wE2, l15, quad, acc);
        const float4 b4 = *(const float4*)(pb2 + f0);
#pragma unroll
        for (int et = 0; et < 4; ++et) {
            const int e = et * 16 + l15;
            acc[et][0] += bf2f((unsigned short)rh[et][0]) + bf2f((unsigned short)rl[et][0]) + b4.x;
            acc[et][1] += bf2f((unsigned short)rh[et][1]) + bf2f((unsigned short)rl[et][1]) + b4.y;
            acc[et][2] += bf2f((unsigned short)rh[et][2]) + bf2f((unsigned short)rl[et][2]) + b4.z;
            acc[et][3] += bf2f((unsigned short)rh[et][3]) + bf2f((unsigned short)rl[et][3]) + b4.w;
            store_row4(pEhi, pElo, acc[et], e, f0);   // own cells, same thread
        }
    }
    __syncthreads();

    // fused aggregation: agg[dst] += e2
    segsum_atomic(pEhi, pElo, sDst, t, agg);
}

// ---------------- K3: node update l0 + layer-1 projections (+ agg self-zero) -----

__global__ __launch_bounds__(256, 4) void k_node_l0(
    float* x_h, float* agg, const unsigned short* __restrict__ wt,
    const float* __restrict__ nb1, const float* __restrict__ nb2,
    float* Ps, float* __restrict__ Pd)
{
    __shared__ unsigned short pXhi[EPB * LDK], pXlo[EPB * LDK];
    __shared__ unsigned short pAhi[EPB * LDK], pAlo[EPB * LDK];

    const int t = threadIdx.x;
    const int lane = t & 63, ft = t >> 6;
    const int quad = lane >> 4, l15 = lane & 15;
    const int f0 = ft * 16 + quad * 4;
    const int nodeBase = blockIdx.x * 64;
    const int nValid = min(64, NN - nodeBase);

    // hoist first-phase weight sets (overlap with staging)
    short8 wNX[2][2], wNA[2][2];
    load_wf(wt + S_W1NX0 * 8192, ft, l15, quad, wNX);
    load_wf(wt + S_W1NA0 * 8192, ft, l15, quad, wNA);

    stage_split64(pXhi, pXlo, x_h, nodeBase, t, nValid);
    stage_split64(pAhi, pAlo, agg, nodeBase, t, nValid);
    __syncthreads();

    // zero own agg slice for layer-1 (replaces memset#2; reads done above)
    {
        const uint4 z4 = {0u, 0u, 0u, 0u};
        uint4* ag = (uint4*)(agg + (size_t)nodeBase * HH);
#pragma unroll
        for (int j = 0; j < 4; ++j) {
            const int di = t + j * 256;
            if (nodeBase + (di >> 4) < NN) ag[di] = z4;
        }
    }

    f32x4 acc[4];

    // t1 = relu(x_h @ W1x + agg @ W1a + nb1)
    {
        set_bias(acc, nb1, f0);
        gemm_planes(pXhi, pXlo, wNX, l15, quad, acc);
        gemm_planes(pAhi, pAlo, wNA, l15, quad, acc);
        relu4(acc);
    }
    __syncthreads();                       // pA reads complete
    store_split_planes(pAhi, pAlo, acc, l15, f0);   // t1 -> pA
    __syncthreads();

    // x_h1 = x_h + t1 @ W2n + nb2 -> global + pX
    {
        short8 w[2][2];
        load_wf(wt + S_W2N0 * 8192, ft, l15, quad, w);
        set_bias(acc, nb2, f0);
        gemm_planes(pAhi, pAlo, w, l15, quad, acc);
#pragma unroll
        for (int et = 0; et < 4; ++et) {
            const int r = et * 16 + l15;
            if (r < nValid) {
                const size_t gi = (size_t)(nodeBase + r) * HH + f0;
                const float4 xr = *(const float4*)(x_h + gi);
                acc[et][0] += xr.x; acc[et][1] += xr.y;
                acc[et][2] += xr.z; acc[et][3] += xr.w;
                float4 v = make_float4(acc[et][0], acc[et][1], acc[et][2], acc[et][3]);
                *(float4*)(x_h + gi) = v;
            }
        }
        store_split_planes(pXhi, pXlo, acc, l15, f0);
    }
    __syncthreads();

    // Ps1 = x_h1 @ W1s(l1)
    {
        short8 w[2][2];
        load_wf(wt + S_W1S1 * 8192, ft, l15, quad, w);
        set_zero(acc);
        gemm_planes(pXhi, pXlo, w, l15, quad, acc);
#pragma unroll
        for (int et = 0; et < 4; ++et) {
            const int r = et * 16 + l15;
            if (r < nValid) {
                float4 v = make_float4(acc[et][0], acc[et][1], acc[et][2], acc[et][3]);
                *(float4*)(Ps + (size_t)(nodeBase + r) * HH + f0) = v;
            }
        }
    }
    // Pd1 = x_h1 @ W1d(l1)
    {
        short8 w[2][2];
        load_wf(wt + S_W1D1 * 8192, ft, l15, quad, w);
        set_zero(acc);
        gemm_planes(pXhi, pXlo, w, l15, quad, acc);
#pragma unroll
        for (int et = 0; et < 4; ++et) {
            const int r = et * 16 + l15;
            if (r < nValid) {
                float4 v = make_float4(acc[et][0], acc[et][1], acc[et][2], acc[et][3]);
                *(float4*)(Pd + (size_t)(nodeBase + r) * HH + f0) = v;
            }
        }
    }
}

// ---------------- K5: node update l1 + decoder ----------------

__global__ __launch_bounds__(256, 4) void k_node_l1_dec(
    const float* x_h, const float* agg, const unsigned short* __restrict__ wt,
    const float* __restrict__ nb1, const float* __restrict__ nb2,
    const float* __restrict__ db1, const float* __restrict__ dw2,
    const float* __restrict__ db2, float* __restrict__ out)
{
    __shared__ unsigned short pXhi[EPB * LDK], pXlo[EPB * LDK];
    __shared__ unsigned short pAhi[EPB * LDK], pAlo[EPB * LDK];
    __shared__ float sW2[64 * 6];

    const int t = threadIdx.x;
    const int lane = t & 63, ft = t >> 6;
    const int quad = lane >> 4, l15 = lane & 15;
    const int f0 = ft * 16 + quad * 4;
    const int nodeBase = blockIdx.x * 64;
    const int nValid = min(64, NN - nodeBase);

    // hoist first-phase weight sets (overlap with staging)
    short8 wNX[2][2], wNA[2][2];
    load_wf(wt + S_W1NX1 * 8192, ft, l15, quad, wNX);
    load_wf(wt + S_W1NA1 * 8192, ft, l15, quad, wNA);

    stage_split64(pXhi, pXlo, x_h, nodeBase, t, nValid);
    stage_split64(pAhi, pAlo, agg, nodeBase, t, nValid);
    if (t < 192) {
        sW2[t] = dw2[t];
        sW2[t + 192] = dw2[t + 192];
    }
    __syncthreads();

    f32x4 acc[4];

    // t1 = relu(x_h @ W1x + agg @ W1a + nb1)
    {
        set_bias(acc, nb1, f0);
        gemm_planes(pXhi, pXlo, wNX, l15, quad, acc);
        gemm_planes(pAhi, pAlo, wNA, l15, quad, acc);
        relu4(acc);
    }
    __syncthreads();
    store_split_planes(pAhi, pAlo, acc, l15, f0);   // t1 -> pA
    __syncthreads();

    // x_h2 = x_h + t1 @ W2n + nb2 -> pX (no global writeback needed)
    {
        short8 w[2][2];
        load_wf(wt + S_W2N1 * 8192, ft, l15, quad, w);
        set_bias(acc, nb2, f0);
        gemm_planes(pAhi, pAlo, w, l15, quad, acc);
#pragma unroll
        for (int et = 0; et < 4; ++et) {
            const int r = et * 16 + l15;
            if (r < nValid) {
                const float4 xr = *(const float4*)(x_h + (size_t)(nodeBase + r) * HH + f0);
                acc[et][0] += xr.x; acc[et][1] += xr.y;
                acc[et][2] += xr.z; acc[et][3] += xr.w;
            }
        }
        store_split_planes(pXhi, pXlo, acc, l15, f0);
    }
    __syncthreads();

    // d1 = relu(x_h2 @ dec_w1 + db1) -> pA
    {
        short8 w[2][2];
        load_wf(wt + S_DW1 * 8192, ft, l15, quad, w);
        set_bias(acc, db1, f0);
        gemm_planes(pXhi, pXlo, w, l15, quad, acc);
        relu4(acc);
        store_split_planes(pAhi, pAlo, acc, l15, f0);
    }
    __syncthreads();

    // out = d1 @ dec_w2 + db2  (64 nodes x 6)
    if (t < 64 && t < nValid) {
        float o[6];
#pragma unroll
        for (int c = 0; c < 6; ++c) o[c] = db2[c];
#pragma unroll 8
        for (int k = 0; k < 64; ++k) {
            const float a = bf2f(pAhi[t * LDK + k]) + bf2f(pAlo[t * LDK + k]);
#pragma unroll
            for (int c = 0; c < 6; ++c) o[c] = fmaf(a, sW2[k * 6 + c], o[c]);
        }
        float* op = out + (size_t)(nodeBase + t) * 6;
#pragma unroll
        for (int c = 0; c < 6; ++c) op[c] = o[c];
    }
}

// ---------------- launcher ----------------

extern "C" void kernel_launch(void* const* d_in, const int* in_sizes, int n_in,
                              void* d_out, int out_size, void* d_ws, size_t ws_size,
                              hipStream_t stream) {
    const float* x        = (const float*)d_in[0];
    const float* eattr    = (const float*)d_in[1];
    const int*   eidx     = (const int*)d_in[2];
    const float* enc_n_w1 = (const float*)d_in[3];
    const float* enc_n_b1 = (const float*)d_in[4];
    const float* enc_n_w2 = (const float*)d_in[5];
    const float* enc_n_b2 = (const float*)d_in[6];
    const float* enc_e_w1 = (const float*)d_in[7];
    const float* enc_e_b1 = (const float*)d_in[8];
    const float* enc_e_w2 = (const float*)d_in[9];
    const float* enc_e_b2 = (const float*)d_in[10];
    const float* pe_w1    = (const float*)d_in[11];  // [2,192,64]
    const float* pe_b1    = (const float*)d_in[12];  // [2,64]
    const float* pe_w2    = (const float*)d_in[13];  // [2,64,64]
    const float* pe_b2    = (const float*)d_in[14];  // [2,64]
    const float* pn_w1    = (const float*)d_in[15];  // [2,128,64]
    const float* pn_b1    = (const float*)d_in[16];
    const float* pn_w2    = (const float*)d_in[17];  // [2,64,64]
    const float* pn_b2    = (const float*)d_in[18];
    const float* dw1      = (const float*)d_in[19];
    const float* db1      = (const float*)d_in[20];
    const float* dw2      = (const float*)d_in[21];
    const float* db2      = (const float*)d_in[22];
    float* out = (float*)d_out;

    // ws: x_h | Ps | Pd | agg | epkHi|epkLo | sd(int2) | csr | off | deg | wt
    const size_t NNHH = (size_t)NN * HH;
    float* ws  = (float*)d_ws;
    float* x_h = ws;
    float* Ps  = ws + NNHH;
    float* Pd  = ws + 2 * NNHH;
    float* agg = ws + 3 * NNHH;
    unsigned short* epkHi = (unsigned short*)(ws + 4 * NNHH);   // EE*HH ushorts
    unsigned short* epkLo = epkHi + (size_t)EE * HH;            // EE*HH ushorts
    int2* sd    = (int2*)(epkLo + (size_t)EE * HH);             // EE int2 (src,dst)
    int* csr    = (int*)(sd + EE);                              // EE
    unsigned* off = (unsigned*)(csr + EE);                      // NN+4 (padded)
    unsigned* deg = off + (NN + 4);                             // NN, reused as cursor
    unsigned short* wt = (unsigned short*)(deg + NN);           // WT_USHORTS (16B-aligned)
    const float* fb = (const float*)(wt + FB_OFF);              // fused biases

    const int nodeBlocks = (NN + 63) / 64;   // 782
    const int edgeBlocks = EE / EPB;         // 12500
    const int eScal      = (EE + 255) / 256; // 3125 (= FILL_BLOCKS)
    const int convBlocks = (73728 + 3 * 4096 + 192 + NN + 255) / 256;  // 533

    k_conv_w<<<convBlocks, 256, 0, stream>>>(
        enc_n_w1, enc_n_w2, enc_e_w1, enc_e_w2,
        pe_w1, pe_w2, pn_w1, pn_w2, dw1,
        enc_n_b2, enc_e_b2, wt, deg);

    k_deg<<<eScal, 256, 0, stream>>>(eidx, deg);
    k_scan<<<1, 1024, 0, stream>>>(deg, off);

    k_fill_encode<<<FILL_BLOCKS + nodeBlocks, 256, 0, stream>>>(
        eidx, deg, csr, sd,
        x, wt, fb, enc_n_b1, enc_n_b2, x_h, Ps, Pd, agg);

    k_edge_l0<<<edgeBlocks, 256, 0, stream>>>(
        eattr, csr, sd, Ps, Pd,
        enc_e_w1, enc_e_b1, enc_e_b2, wt, fb, pe_b1, pe_b2, epkHi, epkLo, agg);

    k_node_l0<<<nodeBlocks, 256, 0, stream>>>(
        x_h, agg, wt, pn_b1, pn_b2, Ps, Pd);

    k_edge_l1<<<edgeBlocks, 256, 0, stream>>>(
        sd, Ps, Pd, wt, pe_b1 + 64, pe_b2 + 64, epkHi, epkLo, agg);

    k_node_l1_dec<<<nodeBlocks, 256, 0, stream>>>(
        x_h, agg, wt, pn_b1 + 64, pn_b2 + 64,
        db1, dw2, db2, out);
}